// Round 4
// baseline (4730.243 us; speedup 1.0000x reference)
//
#include <hip/hip_runtime.h>
#include <math.h>

#define N_NODES 100000
#define N_EDGES 1600000
#define HDIM 64
#define NBUCK 64
#define SCAN_T 1024
#define SCAN_CHUNK 98    // ceil(100000/1024)
#define NCHUNK 1564      // 2 * ceil(N_NODES/128); chunk = 64 sorted nodes

// ---------------- CSR build ----------------

__global__ __launch_bounds__(256) void k_zero_int(int* __restrict__ p, int n) {
  int i = blockIdx.x * 256 + threadIdx.x;
  if (i < n) p[i] = 0;
}

__global__ __launch_bounds__(256) void k_deg_count(const int* __restrict__ ei,
                                                   int* __restrict__ deg) {
  int e = blockIdx.x * 256 + threadIdx.x;
  if (e < N_EDGES) atomicAdd(&deg[ei[N_EDGES + e]], 1);
}

// single-block exclusive scan of deg[N] -> row_ptr[N+1]
__global__ __launch_bounds__(SCAN_T) void k_rowptr(const int* __restrict__ deg,
                                                   int* __restrict__ row_ptr) {
  __shared__ int sums[SCAN_T];
  const int t = threadIdx.x;
  const int lo = t * SCAN_CHUNK;
  const int hi = min(lo + SCAN_CHUNK, N_NODES);
  int s = 0;
  for (int i = lo; i < hi; ++i) s += deg[i];
  sums[t] = s;
  __syncthreads();
  for (int off = 1; off < SCAN_T; off <<= 1) {
    int v = (t >= off) ? sums[t - off] : 0;
    __syncthreads();
    sums[t] += v;
    __syncthreads();
  }
  int run = (t == 0) ? 0 : sums[t - 1];
  for (int i = lo; i < hi; ++i) { row_ptr[i] = run; run += deg[i]; }
  if (t == SCAN_T - 1) row_ptr[N_NODES] = run;
}

__global__ __launch_bounds__(256) void k_scatter(
    const int* __restrict__ ei, const float* __restrict__ eattr,
    const int* __restrict__ row_ptr, int* __restrict__ cursor,
    int* __restrict__ s_src, float* __restrict__ s_ea) {
  int e = blockIdx.x * 256 + threadIdx.x;
  if (e >= N_EDGES) return;
  int d = ei[N_EDGES + e];
  int pos = row_ptr[d] + atomicAdd(&cursor[d], 1);
  s_src[pos] = ei[e];
  s_ea[pos] = eattr[e];
}

__global__ __launch_bounds__(256) void k_bucket_hist(const int* __restrict__ deg,
                                                     int* __restrict__ bhist) {
  int i = blockIdx.x * 256 + threadIdx.x;
  if (i < N_NODES) atomicAdd(&bhist[min(deg[i], NBUCK - 1)], 1);
}

__global__ __launch_bounds__(64) void k_bucket_scan(const int* __restrict__ bhist,
                                                    int* __restrict__ bcursor) {
  if (threadIdx.x == 0) {
    int run = 0;
    for (int b = 0; b < NBUCK; ++b) { bcursor[b] = run; run += bhist[b]; }
  }
}

__global__ __launch_bounds__(256) void k_bucket_scatter(const int* __restrict__ deg,
                                                        int* __restrict__ bcursor,
                                                        int* __restrict__ node_order) {
  __shared__ int lhist[NBUCK];
  __shared__ int lbase[NBUCK];
  __shared__ int lcur[NBUCK];
  const int t = threadIdx.x;
  const int i = blockIdx.x * 256 + t;
  if (t < NBUCK) { lhist[t] = 0; lcur[t] = 0; }
  __syncthreads();
  int b = -1;
  if (i < N_NODES) { b = min(deg[i], NBUCK - 1); atomicAdd(&lhist[b], 1); }
  __syncthreads();
  if (t < NBUCK && lhist[t] > 0) lbase[t] = atomicAdd(&bcursor[t], lhist[t]);
  __syncthreads();
  if (i < N_NODES) {
    int r = atomicAdd(&lcur[b], 1);
    node_order[lbase[b] + r] = i;
  }
}

// ---------------- per-layer kernels ----------------

// h = x*emb_w + emb_b (NF==1), then z = h @ W1a[0] + b1[0].
__global__ __launch_bounds__(256) void k_embed_z(
    const float* __restrict__ x, const float* __restrict__ emb_w,
    const float* __restrict__ emb_b,
    const float* __restrict__ w1, const float* __restrict__ b1,
    float* __restrict__ h, float* __restrict__ z) {
  __shared__ float hs[64][65];
  const int t = threadIdx.x;
  const int nl = t >> 2;
  const int l4 = t & 3;
  const int i = blockIdx.x * 64 + nl;
  const bool valid = (i < N_NODES);
  const int jbase = l4 * 16;
  const float xv = valid ? x[i] : 0.0f;

  float hv[16];
  #pragma unroll
  for (int jj = 0; jj < 16; ++jj) {
    int j = jbase + jj;
    hv[jj] = fmaf(xv, emb_w[j], emb_b[j]);
    hs[nl][j] = hv[jj];
  }
  if (valid) {
    #pragma unroll
    for (int q = 0; q < 4; ++q)
      reinterpret_cast<float4*>(h + (size_t)i * HDIM)[l4 * 4 + q] =
          make_float4(hv[4*q], hv[4*q+1], hv[4*q+2], hv[4*q+3]);
  }
  __syncthreads();

  float acc[16];
  #pragma unroll
  for (int jj = 0; jj < 16; ++jj) acc[jj] = b1[jbase + jj];
  #pragma unroll 8
  for (int k = 0; k < 64; ++k) {
    float hk = hs[nl][k];
    const float* wr = w1 + k * 64 + jbase;
    #pragma unroll
    for (int jj = 0; jj < 16; ++jj) acc[jj] = fmaf(hk, wr[jj], acc[jj]);
  }
  if (valid) {
    #pragma unroll
    for (int q = 0; q < 4; ++q)
      reinterpret_cast<float4*>(z + (size_t)i * HDIM)[l4 * 4 + q] =
          make_float4(acc[4*q], acc[4*q+1], acc[4*q+2], acc[4*q+3]);
  }
}

// Aggregation: 4 waves/block. Wave-pair `pair` covers one 64-node chunk,
// halves 0/1 each compute 32 output cols. Chunk mapping pairs cheap chunk b
// with expensive chunk NCHUNK-1-b (degree-sorted) for block balance.
// z row double-buffered in registers: edge p+1's gather issues before edge
// p's ~4350-cycle FMA block.
__global__ __launch_bounds__(256, 2) void k_aggr3(
    const int* __restrict__ node_order, const int* __restrict__ row_ptr,
    const int* __restrict__ s_src, const float* __restrict__ s_ea,
    const float* __restrict__ z,
    const float* __restrict__ w1b, const float* __restrict__ w2,
    const float* __restrict__ b2,
    float* __restrict__ aggr) {
  const int t = threadIdx.x;
  const int lane = t & 63;
  const int wv = t >> 6;
  const int half = __builtin_amdgcn_readfirstlane(wv & 1);
  const int pair = __builtin_amdgcn_readfirstlane(wv >> 1);
  const int jb = half * 32;
  const int chunk = pair ? (NCHUNK - 1 - (int)blockIdx.x) : (int)blockIdx.x;
  const int r = chunk * 64 + lane;
  if (r >= N_NODES) return;
  const int node = node_order[r];
  const int p0 = row_ptr[node];
  const int p1 = row_ptr[node + 1];

  float mn[32];
  #pragma unroll
  for (int j = 0; j < 32; ++j) mn[j] = INFINITY;

  float4 zb[16];
  float eab = 0.0f;
  if (p0 < p1) {
    const float4* zr = reinterpret_cast<const float4*>(z + (size_t)s_src[p0] * HDIM);
    #pragma unroll
    for (int q = 0; q < 16; ++q) zb[q] = zr[q];
    eab = s_ea[p0];
  }

  for (int p = p0; p < p1; ++p) {
    // ---- prefetch edge p+1 ----
    float4 zn[16];
    float ean = 0.0f;
    const int pn = p + 1;
    if (pn < p1) {
      const float4* zr = reinterpret_cast<const float4*>(z + (size_t)s_src[pn] * HDIM);
      #pragma unroll
      for (int q = 0; q < 16; ++q) zn[q] = zr[q];
      ean = s_ea[pn];
    }

    // ---- compute edge p from zb/eab ----
    float m[32];
    #pragma unroll
    for (int j = 0; j < 32; ++j) m[j] = b2[jb + j];

    #pragma unroll
    for (int k4 = 0; k4 < 16; ++k4) {
      float4 zv = zb[k4];
      float h0 = fmaxf(fmaf(eab, w1b[4*k4+0], zv.x), 0.0f);
      float h1 = fmaxf(fmaf(eab, w1b[4*k4+1], zv.y), 0.0f);
      float h2 = fmaxf(fmaf(eab, w1b[4*k4+2], zv.z), 0.0f);
      float h3 = fmaxf(fmaf(eab, w1b[4*k4+3], zv.w), 0.0f);
      const float* wr0 = w2 + (4*k4+0) * 64 + jb;
      const float* wr1 = w2 + (4*k4+1) * 64 + jb;
      const float* wr2 = w2 + (4*k4+2) * 64 + jb;
      const float* wr3 = w2 + (4*k4+3) * 64 + jb;
      #pragma unroll
      for (int j = 0; j < 32; ++j) m[j] = fmaf(h0, wr0[j], m[j]);
      #pragma unroll
      for (int j = 0; j < 32; ++j) m[j] = fmaf(h1, wr1[j], m[j]);
      #pragma unroll
      for (int j = 0; j < 32; ++j) m[j] = fmaf(h2, wr2[j], m[j]);
      #pragma unroll
      for (int j = 0; j < 32; ++j) m[j] = fmaf(h3, wr3[j], m[j]);
    }
    #pragma unroll
    for (int j = 0; j < 32; ++j) mn[j] = fminf(mn[j], m[j]);

    // ---- rotate buffers ----
    #pragma unroll
    for (int q = 0; q < 16; ++q) zb[q] = zn[q];
    eab = ean;
  }

  float4* ar = reinterpret_cast<float4*>(aggr + (size_t)node * HDIM + jb);
  #pragma unroll
  for (int q = 0; q < 8; ++q) {
    float4 v;
    v.x = isinf(mn[4*q+0]) ? 0.0f : mn[4*q+0];
    v.y = isinf(mn[4*q+1]) ? 0.0f : mn[4*q+1];
    v.z = isinf(mn[4*q+2]) ? 0.0f : mn[4*q+2];
    v.w = isinf(mn[4*q+3]) ? 0.0f : mn[4*q+3];
    ar[q] = v;
  }
}

// Update: wave-pair structure. u = [h, aggr] streamed from global;
// weights via s_load; h1/hn exchanged through one LDS buffer.
template <int LAST>
__global__ __launch_bounds__(256) void k_update2(
    const float* __restrict__ aggr,
    const float* __restrict__ u1w, const float* __restrict__ u1b,
    const float* __restrict__ u2w, const float* __restrict__ u2b,
    const float* __restrict__ w1next, const float* __restrict__ b1next,
    const float* __restrict__ fcw, const float* __restrict__ fcb,
    float* __restrict__ h, float* __restrict__ z, float* __restrict__ out) {
  __shared__ float h1s[128][65];
  const int t = threadIdx.x;
  const int lane = t & 63;
  const int wv = t >> 6;
  const int half = __builtin_amdgcn_readfirstlane(wv & 1);
  const int pair = __builtin_amdgcn_readfirstlane(wv >> 1);
  const int jb = half * 32;
  const int nl = pair * 64 + lane;            // 0..127
  const int node = blockIdx.x * 128 + nl;
  const bool valid = (node < N_NODES);
  const size_t off = (size_t)(valid ? node : 0) * HDIM;

  // ---- phase 1: acc[32] = (u @ U1 + b1)[jb..jb+32), u = [h, aggr] ----
  float acc[32];
  #pragma unroll
  for (int j = 0; j < 32; ++j) acc[j] = u1b[jb + j];
  {
    const float4* hr = reinterpret_cast<const float4*>(h + off);
    for (int k4 = 0; k4 < 16; ++k4) {
      float4 uv = hr[k4];
      const float* w0 = u1w + (4*k4+0) * 64 + jb;
      const float* w1 = u1w + (4*k4+1) * 64 + jb;
      const float* w2 = u1w + (4*k4+2) * 64 + jb;
      const float* w3 = u1w + (4*k4+3) * 64 + jb;
      #pragma unroll
      for (int j = 0; j < 32; ++j) acc[j] = fmaf(uv.x, w0[j], acc[j]);
      #pragma unroll
      for (int j = 0; j < 32; ++j) acc[j] = fmaf(uv.y, w1[j], acc[j]);
      #pragma unroll
      for (int j = 0; j < 32; ++j) acc[j] = fmaf(uv.z, w2[j], acc[j]);
      #pragma unroll
      for (int j = 0; j < 32; ++j) acc[j] = fmaf(uv.w, w3[j], acc[j]);
    }
    const float4* ar = reinterpret_cast<const float4*>(aggr + off);
    for (int k4 = 0; k4 < 16; ++k4) {
      float4 uv = ar[k4];
      const float* w0 = u1w + (64 + 4*k4+0) * 64 + jb;
      const float* w1 = u1w + (64 + 4*k4+1) * 64 + jb;
      const float* w2 = u1w + (64 + 4*k4+2) * 64 + jb;
      const float* w3 = u1w + (64 + 4*k4+3) * 64 + jb;
      #pragma unroll
      for (int j = 0; j < 32; ++j) acc[j] = fmaf(uv.x, w0[j], acc[j]);
      #pragma unroll
      for (int j = 0; j < 32; ++j) acc[j] = fmaf(uv.y, w1[j], acc[j]);
      #pragma unroll
      for (int j = 0; j < 32; ++j) acc[j] = fmaf(uv.z, w2[j], acc[j]);
      #pragma unroll
      for (int j = 0; j < 32; ++j) acc[j] = fmaf(uv.w, w3[j], acc[j]);
    }
  }
  #pragma unroll
  for (int j = 0; j < 32; ++j) h1s[nl][jb + j] = fmaxf(acc[j], 0.0f);
  __syncthreads();

  // ---- phase 2: hn[32] = (relu(h1) @ U2 + b2)[jb..jb+32) ----
  float hn[32];
  #pragma unroll
  for (int j = 0; j < 32; ++j) hn[j] = u2b[jb + j];
  for (int k = 0; k < 64; ++k) {
    float hk = h1s[nl][k];
    const float* wr = u2w + k * 64 + jb;
    #pragma unroll
    for (int j = 0; j < 32; ++j) hn[j] = fmaf(hk, wr[j], hn[j]);
  }
  if (valid) {
    #pragma unroll
    for (int q = 0; q < 8; ++q)
      reinterpret_cast<float4*>(h + off)[half * 8 + q] =
          make_float4(hn[4*q], hn[4*q+1], hn[4*q+2], hn[4*q+3]);
  }

  if (LAST) {
    float s = 0.0f;
    #pragma unroll
    for (int j = 0; j < 32; ++j) s = fmaf(hn[j], fcw[jb + j], s);
    __syncthreads();
    if (half) h1s[nl][64] = s;
    __syncthreads();
    if (!half && valid) out[node] = s + h1s[nl][64] + fcb[0];
  } else {
    __syncthreads();   // all phase-2 LDS reads done before overwrite
    #pragma unroll
    for (int j = 0; j < 32; ++j) h1s[nl][jb + j] = hn[j];
    __syncthreads();
    // ---- phase 3: z = hn @ W1a_next + b1_next ----
    float zz[32];
    #pragma unroll
    for (int j = 0; j < 32; ++j) zz[j] = b1next[jb + j];
    for (int k = 0; k < 64; ++k) {
      float hk = h1s[nl][k];
      const float* wr = w1next + k * 64 + jb;
      #pragma unroll
      for (int j = 0; j < 32; ++j) zz[j] = fmaf(hk, wr[j], zz[j]);
    }
    if (valid) {
      #pragma unroll
      for (int q = 0; q < 8; ++q)
        reinterpret_cast<float4*>(z + off)[half * 8 + q] =
            make_float4(zz[4*q], zz[4*q+1], zz[4*q+2], zz[4*q+3]);
    }
  }
}

extern "C" void kernel_launch(void* const* d_in, const int* in_sizes, int n_in,
                              void* d_out, int out_size, void* d_ws, size_t ws_size,
                              hipStream_t stream) {
  const float* x      = (const float*)d_in[0];
  const int*   ei     = (const int*)d_in[1];
  const float* eattr  = (const float*)d_in[2];
  const float* emb_w  = (const float*)d_in[3];
  const float* emb_b  = (const float*)d_in[4];
  const float* msg_w1 = (const float*)d_in[5];
  const float* msg_b1 = (const float*)d_in[6];
  const float* msg_w2 = (const float*)d_in[7];
  const float* msg_b2 = (const float*)d_in[8];
  const float* upd_w1 = (const float*)d_in[9];
  const float* upd_b1 = (const float*)d_in[10];
  const float* upd_w2 = (const float*)d_in[11];
  const float* upd_b2 = (const float*)d_in[12];
  const float* fc_w   = (const float*)d_in[13];
  const float* fc_b   = (const float*)d_in[14];
  float* out = (float*)d_out;

  // workspace layout
  float* h     = (float*)d_ws;                          // N*64
  float* zbuf  = h + (size_t)N_NODES * HDIM;            // N*64
  float* aggr  = zbuf + (size_t)N_NODES * HDIM;         // N*64
  float* s_ea  = aggr + (size_t)N_NODES * HDIM;         // E
  int*   s_src = (int*)(s_ea + N_EDGES);                // E
  int*   row_ptr = s_src + N_EDGES;                     // N+1
  int*   node_order = row_ptr + (N_NODES + 1);          // N
  int*   deg   = node_order + N_NODES;                  // N
  int*   cursor= deg + N_NODES;                         // N
  int*   bhist = cursor + N_NODES;                      // NBUCK
  int*   bcursor = bhist + NBUCK;                       // NBUCK

  const int nodeBlocks64 = (N_NODES + 63) / 64;
  const int nodeBlocks128 = (N_NODES + 127) / 128;      // 782 == NCHUNK/2
  const int nodeBlocks256 = (N_NODES + 255) / 256;
  const int edgeBlocks = (N_EDGES + 255) / 256;
  const int zeroN = 2 * N_NODES + NBUCK;  // deg, cursor, bhist contiguous

  // ---- CSR + degree-sort build (once per launch) ----
  k_zero_int<<<(zeroN + 255) / 256, 256, 0, stream>>>(deg, zeroN);
  k_deg_count<<<edgeBlocks, 256, 0, stream>>>(ei, deg);
  k_rowptr<<<1, SCAN_T, 0, stream>>>(deg, row_ptr);
  k_scatter<<<edgeBlocks, 256, 0, stream>>>(ei, eattr, row_ptr, cursor, s_src, s_ea);
  k_bucket_hist<<<nodeBlocks256, 256, 0, stream>>>(deg, bhist);
  k_bucket_scan<<<1, 64, 0, stream>>>(bhist, bcursor);
  k_bucket_scatter<<<nodeBlocks256, 256, 0, stream>>>(deg, bcursor, node_order);

  // ---- layers ----
  k_embed_z<<<nodeBlocks64, 256, 0, stream>>>(x, emb_w, emb_b, msg_w1, msg_b1, h, zbuf);

  for (int l = 0; l < 5; ++l) {
    k_aggr3<<<nodeBlocks128, 256, 0, stream>>>(
        node_order, row_ptr, s_src, s_ea, zbuf,
        msg_w1 + l * 65 * 64 + 64 * 64,   // w1b: row 64 (edge_attr coeffs)
        msg_w2 + l * 64 * 64,
        msg_b2 + l * 64,
        aggr);
    if (l < 4) {
      k_update2<0><<<nodeBlocks128, 256, 0, stream>>>(
          aggr,
          upd_w1 + l * 128 * 64, upd_b1 + l * 64,
          upd_w2 + l * 64 * 64,  upd_b2 + l * 64,
          msg_w1 + (l + 1) * 65 * 64, msg_b1 + (l + 1) * 64,
          nullptr, nullptr,
          h, zbuf, nullptr);
    } else {
      k_update2<1><<<nodeBlocks128, 256, 0, stream>>>(
          aggr,
          upd_w1 + l * 128 * 64, upd_b1 + l * 64,
          upd_w2 + l * 64 * 64,  upd_b2 + l * 64,
          nullptr, nullptr,
          fc_w, fc_b,
          h, zbuf, out);
    }
  }
}

// Round 5
// 2688.342 us; speedup vs baseline: 1.7595x; 1.7595x over previous
//
#include <hip/hip_runtime.h>
#include <math.h>

#define N_NODES 100000
#define N_EDGES 1600000
#define HDIM 64
#define NBUCK 64
#define SCAN_T 1024
#define SCAN_CHUNK 98    // ceil(100000/1024)
#define NPB 128          // nodes per block (2 adjacent 64-node sorted chunks)
#define LBLOCKS 782      // ceil(100000/128)

// ---------------- CSR build ----------------

__global__ __launch_bounds__(256) void k_zero_int(int* __restrict__ p, int n) {
  int i = blockIdx.x * 256 + threadIdx.x;
  if (i < n) p[i] = 0;
}

__global__ __launch_bounds__(256) void k_deg_count(const int* __restrict__ ei,
                                                   int* __restrict__ deg) {
  int e = blockIdx.x * 256 + threadIdx.x;
  if (e < N_EDGES) atomicAdd(&deg[ei[N_EDGES + e]], 1);
}

// single-block exclusive scan of deg[N] -> row_ptr[N+1]
__global__ __launch_bounds__(SCAN_T) void k_rowptr(const int* __restrict__ deg,
                                                   int* __restrict__ row_ptr) {
  __shared__ int sums[SCAN_T];
  const int t = threadIdx.x;
  const int lo = t * SCAN_CHUNK;
  const int hi = min(lo + SCAN_CHUNK, N_NODES);
  int s = 0;
  for (int i = lo; i < hi; ++i) s += deg[i];
  sums[t] = s;
  __syncthreads();
  for (int off = 1; off < SCAN_T; off <<= 1) {
    int v = (t >= off) ? sums[t - off] : 0;
    __syncthreads();
    sums[t] += v;
    __syncthreads();
  }
  int run = (t == 0) ? 0 : sums[t - 1];
  for (int i = lo; i < hi; ++i) { row_ptr[i] = run; run += deg[i]; }
  if (t == SCAN_T - 1) row_ptr[N_NODES] = run;
}

__global__ __launch_bounds__(256) void k_scatter(
    const int* __restrict__ ei, const float* __restrict__ eattr,
    const int* __restrict__ row_ptr, int* __restrict__ cursor,
    int* __restrict__ s_src, float* __restrict__ s_ea) {
  int e = blockIdx.x * 256 + threadIdx.x;
  if (e >= N_EDGES) return;
  int d = ei[N_EDGES + e];
  int pos = row_ptr[d] + atomicAdd(&cursor[d], 1);
  s_src[pos] = ei[e];
  s_ea[pos] = eattr[e];
}

__global__ __launch_bounds__(256) void k_bucket_hist(const int* __restrict__ deg,
                                                     int* __restrict__ bhist) {
  int i = blockIdx.x * 256 + threadIdx.x;
  if (i < N_NODES) atomicAdd(&bhist[min(deg[i], NBUCK - 1)], 1);
}

__global__ __launch_bounds__(64) void k_bucket_scan(const int* __restrict__ bhist,
                                                    int* __restrict__ bcursor) {
  if (threadIdx.x == 0) {
    int run = 0;
    for (int b = 0; b < NBUCK; ++b) { bcursor[b] = run; run += bhist[b]; }
  }
}

__global__ __launch_bounds__(256) void k_bucket_scatter(const int* __restrict__ deg,
                                                        int* __restrict__ bcursor,
                                                        int* __restrict__ node_order) {
  __shared__ int lhist[NBUCK];
  __shared__ int lbase[NBUCK];
  __shared__ int lcur[NBUCK];
  const int t = threadIdx.x;
  const int i = blockIdx.x * 256 + t;
  if (t < NBUCK) { lhist[t] = 0; lcur[t] = 0; }
  __syncthreads();
  int b = -1;
  if (i < N_NODES) { b = min(deg[i], NBUCK - 1); atomicAdd(&lhist[b], 1); }
  __syncthreads();
  if (t < NBUCK && lhist[t] > 0) lbase[t] = atomicAdd(&bcursor[t], lhist[t]);
  __syncthreads();
  if (i < N_NODES) {
    int r = atomicAdd(&lcur[b], 1);
    node_order[lbase[b] + r] = i;
  }
}

// ---------------- embed ----------------

// h = x*emb_w + emb_b (NF==1), then z = h @ W1a[0] + b1[0].
__global__ __launch_bounds__(256) void k_embed_z(
    const float* __restrict__ x, const float* __restrict__ emb_w,
    const float* __restrict__ emb_b,
    const float* __restrict__ w1, const float* __restrict__ b1,
    float* __restrict__ h, float* __restrict__ z) {
  __shared__ float hs[64][65];
  const int t = threadIdx.x;
  const int nl = t >> 2;
  const int l4 = t & 3;
  const int i = blockIdx.x * 64 + nl;
  const bool valid = (i < N_NODES);
  const int jbase = l4 * 16;
  const float xv = valid ? x[i] : 0.0f;

  float hv[16];
  #pragma unroll
  for (int jj = 0; jj < 16; ++jj) {
    int j = jbase + jj;
    hv[jj] = fmaf(xv, emb_w[j], emb_b[j]);
    hs[nl][j] = hv[jj];
  }
  if (valid) {
    #pragma unroll
    for (int q = 0; q < 4; ++q)
      reinterpret_cast<float4*>(h + (size_t)i * HDIM)[l4 * 4 + q] =
          make_float4(hv[4*q], hv[4*q+1], hv[4*q+2], hv[4*q+3]);
  }
  __syncthreads();

  float acc[16];
  #pragma unroll
  for (int jj = 0; jj < 16; ++jj) acc[jj] = b1[jbase + jj];
  #pragma unroll 8
  for (int k = 0; k < 64; ++k) {
    float hk = hs[nl][k];
    const float* wr = w1 + k * 64 + jbase;
    #pragma unroll
    for (int jj = 0; jj < 16; ++jj) acc[jj] = fmaf(hk, wr[jj], acc[jj]);
  }
  if (valid) {
    #pragma unroll
    for (int q = 0; q < 4; ++q)
      reinterpret_cast<float4*>(z + (size_t)i * HDIM)[l4 * 4 + q] =
          make_float4(acc[4*q], acc[4*q+1], acc[4*q+2], acc[4*q+3]);
  }
}

// ---------------- fused layer kernel ----------------
// 512 threads = 8 waves; 128 nodes/block (2 adjacent degree-sorted chunks,
// heaviest blocks launched first). 4 threads per node, 16 output cols each:
// wave w: q = w&3 (column quarter, wave-uniform -> weights via s_load),
// cw = w>>2 (which 64-node chunk), node-local nl = cw*64 + lane.
// Aggregation result goes to LDS (no global aggr buffer); update MLP chained
// in the same kernel through the single LDS exchange buffer.
// z double-buffered across layers (reads z_in, writes z_out).
template <int LAST>
__global__ __launch_bounds__(512) void k_layer(
    const int* __restrict__ node_order, const int* __restrict__ row_ptr,
    const int* __restrict__ s_src, const float* __restrict__ s_ea,
    const float* __restrict__ z_in,
    const float* __restrict__ w1b, const float* __restrict__ w2,
    const float* __restrict__ b2,
    const float* __restrict__ u1w, const float* __restrict__ u1b,
    const float* __restrict__ u2w, const float* __restrict__ u2b,
    const float* __restrict__ w1next, const float* __restrict__ b1next,
    const float* __restrict__ fcw, const float* __restrict__ fcb,
    float* __restrict__ h, float* __restrict__ z_out, float* __restrict__ out) {
  __shared__ float xch[NPB][65];
  __shared__ float ps[NPB][4];
  const int t = threadIdx.x;
  const int lane = t & 63;
  const int w = t >> 6;
  const int q  = __builtin_amdgcn_readfirstlane(w & 3);
  const int cw = __builtin_amdgcn_readfirstlane(w >> 2);
  const int jb = q * 16;
  const int nl = cw * 64 + lane;                       // 0..127
  const int r = (LBLOCKS - 1 - (int)blockIdx.x) * NPB + nl;  // heavy-first
  const bool valid = (r < N_NODES);
  const int node = valid ? node_order[r] : 0;
  const size_t hoff = (size_t)node * HDIM;

  // ---- aggregation: mn[16] = segment-min over CSR segment ----
  float mn[16];
  #pragma unroll
  for (int j = 0; j < 16; ++j) mn[j] = INFINITY;

  if (valid) {
    const int p0 = row_ptr[node];
    const int p1 = row_ptr[node + 1];
    for (int p = p0; p < p1; ++p) {
      const int src = s_src[p];
      const float ea = s_ea[p];
      const float4* zr = reinterpret_cast<const float4*>(z_in + (size_t)src * HDIM);

      float m[16];
      #pragma unroll
      for (int j = 0; j < 16; ++j) m[j] = b2[jb + j];

      for (int k4 = 0; k4 < 16; ++k4) {
        float4 zv = zr[k4];
        float h0 = fmaxf(fmaf(ea, w1b[4*k4+0], zv.x), 0.0f);
        float h1 = fmaxf(fmaf(ea, w1b[4*k4+1], zv.y), 0.0f);
        float h2 = fmaxf(fmaf(ea, w1b[4*k4+2], zv.z), 0.0f);
        float h3 = fmaxf(fmaf(ea, w1b[4*k4+3], zv.w), 0.0f);
        const float* wr0 = w2 + (4*k4+0) * 64 + jb;
        const float* wr1 = w2 + (4*k4+1) * 64 + jb;
        const float* wr2 = w2 + (4*k4+2) * 64 + jb;
        const float* wr3 = w2 + (4*k4+3) * 64 + jb;
        #pragma unroll
        for (int j = 0; j < 16; ++j) m[j] = fmaf(h0, wr0[j], m[j]);
        #pragma unroll
        for (int j = 0; j < 16; ++j) m[j] = fmaf(h1, wr1[j], m[j]);
        #pragma unroll
        for (int j = 0; j < 16; ++j) m[j] = fmaf(h2, wr2[j], m[j]);
        #pragma unroll
        for (int j = 0; j < 16; ++j) m[j] = fmaf(h3, wr3[j], m[j]);
      }
      #pragma unroll
      for (int j = 0; j < 16; ++j) mn[j] = fminf(mn[j], m[j]);
    }
  }
  #pragma unroll
  for (int j = 0; j < 16; ++j)
    xch[nl][jb + j] = isinf(mn[j]) ? 0.0f : mn[j];
  __syncthreads();

  // ---- update phase 1: acc[16] = (u @ U1 + b1)[jb..), u = [h(global), aggr(LDS)] ----
  float acc[16];
  #pragma unroll
  for (int j = 0; j < 16; ++j) acc[j] = u1b[jb + j];
  {
    const float4* hr = reinterpret_cast<const float4*>(h + hoff);
    for (int k4 = 0; k4 < 16; ++k4) {
      float4 uv = hr[k4];
      const float* w0 = u1w + (4*k4+0) * 64 + jb;
      const float* w1 = u1w + (4*k4+1) * 64 + jb;
      const float* w2r = u1w + (4*k4+2) * 64 + jb;
      const float* w3 = u1w + (4*k4+3) * 64 + jb;
      #pragma unroll
      for (int j = 0; j < 16; ++j) acc[j] = fmaf(uv.x, w0[j], acc[j]);
      #pragma unroll
      for (int j = 0; j < 16; ++j) acc[j] = fmaf(uv.y, w1[j], acc[j]);
      #pragma unroll
      for (int j = 0; j < 16; ++j) acc[j] = fmaf(uv.z, w2r[j], acc[j]);
      #pragma unroll
      for (int j = 0; j < 16; ++j) acc[j] = fmaf(uv.w, w3[j], acc[j]);
    }
    for (int k = 0; k < 64; ++k) {
      float uk = xch[nl][k];
      const float* wr = u1w + (64 + k) * 64 + jb;
      #pragma unroll
      for (int j = 0; j < 16; ++j) acc[j] = fmaf(uk, wr[j], acc[j]);
    }
  }
  __syncthreads();   // all phase-1 LDS reads done
  #pragma unroll
  for (int j = 0; j < 16; ++j) xch[nl][jb + j] = fmaxf(acc[j], 0.0f);
  __syncthreads();

  // ---- update phase 2: hn[16] = (relu(h1) @ U2 + b2)[jb..) ----
  float hn[16];
  #pragma unroll
  for (int j = 0; j < 16; ++j) hn[j] = u2b[jb + j];
  for (int k = 0; k < 64; ++k) {
    float hk = xch[nl][k];
    const float* wr = u2w + k * 64 + jb;
    #pragma unroll
    for (int j = 0; j < 16; ++j) hn[j] = fmaf(hk, wr[j], hn[j]);
  }
  if (valid) {
    #pragma unroll
    for (int v = 0; v < 4; ++v)
      reinterpret_cast<float4*>(h + hoff)[q * 4 + v] =
          make_float4(hn[4*v], hn[4*v+1], hn[4*v+2], hn[4*v+3]);
  }

  if (LAST) {
    float s = 0.0f;
    #pragma unroll
    for (int j = 0; j < 16; ++j) s = fmaf(hn[j], fcw[jb + j], s);
    ps[nl][q] = s;
    __syncthreads();
    if (q == 0 && valid)
      out[node] = ps[nl][0] + ps[nl][1] + ps[nl][2] + ps[nl][3] + fcb[0];
  } else {
    __syncthreads();   // all phase-2 LDS reads done
    #pragma unroll
    for (int j = 0; j < 16; ++j) xch[nl][jb + j] = hn[j];
    __syncthreads();
    // ---- phase 3: z_next = h_new @ W1a_next + b1_next ----
    float zz[16];
    #pragma unroll
    for (int j = 0; j < 16; ++j) zz[j] = b1next[jb + j];
    for (int k = 0; k < 64; ++k) {
      float hk = xch[nl][k];
      const float* wr = w1next + k * 64 + jb;
      #pragma unroll
      for (int j = 0; j < 16; ++j) zz[j] = fmaf(hk, wr[j], zz[j]);
    }
    if (valid) {
      #pragma unroll
      for (int v = 0; v < 4; ++v)
        reinterpret_cast<float4*>(z_out + hoff)[q * 4 + v] =
            make_float4(zz[4*v], zz[4*v+1], zz[4*v+2], zz[4*v+3]);
    }
  }
}

extern "C" void kernel_launch(void* const* d_in, const int* in_sizes, int n_in,
                              void* d_out, int out_size, void* d_ws, size_t ws_size,
                              hipStream_t stream) {
  const float* x      = (const float*)d_in[0];
  const int*   ei     = (const int*)d_in[1];
  const float* eattr  = (const float*)d_in[2];
  const float* emb_w  = (const float*)d_in[3];
  const float* emb_b  = (const float*)d_in[4];
  const float* msg_w1 = (const float*)d_in[5];
  const float* msg_b1 = (const float*)d_in[6];
  const float* msg_w2 = (const float*)d_in[7];
  const float* msg_b2 = (const float*)d_in[8];
  const float* upd_w1 = (const float*)d_in[9];
  const float* upd_b1 = (const float*)d_in[10];
  const float* upd_w2 = (const float*)d_in[11];
  const float* upd_b2 = (const float*)d_in[12];
  const float* fc_w   = (const float*)d_in[13];
  const float* fc_b   = (const float*)d_in[14];
  float* out = (float*)d_out;

  // workspace layout
  float* h     = (float*)d_ws;                          // N*64
  float* zA    = h + (size_t)N_NODES * HDIM;            // N*64
  float* zB    = zA + (size_t)N_NODES * HDIM;           // N*64
  float* s_ea  = zB + (size_t)N_NODES * HDIM;           // E
  int*   s_src = (int*)(s_ea + N_EDGES);                // E
  int*   row_ptr = s_src + N_EDGES;                     // N+1
  int*   node_order = row_ptr + (N_NODES + 1);          // N
  int*   deg   = node_order + N_NODES;                  // N
  int*   cursor= deg + N_NODES;                         // N
  int*   bhist = cursor + N_NODES;                      // NBUCK
  int*   bcursor = bhist + NBUCK;                       // NBUCK

  const int nodeBlocks64 = (N_NODES + 63) / 64;
  const int nodeBlocks256 = (N_NODES + 255) / 256;
  const int edgeBlocks = (N_EDGES + 255) / 256;
  const int zeroN = 2 * N_NODES + NBUCK;  // deg, cursor, bhist contiguous

  // ---- CSR + degree-sort build (once per launch) ----
  k_zero_int<<<(zeroN + 255) / 256, 256, 0, stream>>>(deg, zeroN);
  k_deg_count<<<edgeBlocks, 256, 0, stream>>>(ei, deg);
  k_rowptr<<<1, SCAN_T, 0, stream>>>(deg, row_ptr);
  k_scatter<<<edgeBlocks, 256, 0, stream>>>(ei, eattr, row_ptr, cursor, s_src, s_ea);
  k_bucket_hist<<<nodeBlocks256, 256, 0, stream>>>(deg, bhist);
  k_bucket_scan<<<1, 64, 0, stream>>>(bhist, bcursor);
  k_bucket_scatter<<<nodeBlocks256, 256, 0, stream>>>(deg, bcursor, node_order);

  // ---- embed + fused layers ----
  k_embed_z<<<nodeBlocks64, 256, 0, stream>>>(x, emb_w, emb_b, msg_w1, msg_b1, h, zA);

  float* zin = zA;
  float* zout = zB;
  for (int l = 0; l < 5; ++l) {
    const float* w1b = msg_w1 + l * 65 * 64 + 64 * 64;  // row 64: edge_attr coeffs
    const float* w2  = msg_w2 + l * 64 * 64;
    const float* b2  = msg_b2 + l * 64;
    const float* u1w = upd_w1 + l * 128 * 64;
    const float* u1b = upd_b1 + l * 64;
    const float* u2w = upd_w2 + l * 64 * 64;
    const float* u2b = upd_b2 + l * 64;
    if (l < 4) {
      k_layer<0><<<LBLOCKS, 512, 0, stream>>>(
          node_order, row_ptr, s_src, s_ea, zin,
          w1b, w2, b2, u1w, u1b, u2w, u2b,
          msg_w1 + (l + 1) * 65 * 64, msg_b1 + (l + 1) * 64,
          nullptr, nullptr,
          h, zout, nullptr);
      float* tmp = zin; zin = zout; zout = tmp;
    } else {
      k_layer<1><<<LBLOCKS, 512, 0, stream>>>(
          node_order, row_ptr, s_src, s_ea, zin,
          w1b, w2, b2, u1w, u1b, u2w, u2b,
          nullptr, nullptr,
          fc_w, fc_b,
          h, nullptr, out);
    }
  }
}

// Round 6
// 2560.326 us; speedup vs baseline: 1.8475x; 1.0500x over previous
//
#include <hip/hip_runtime.h>
#include <math.h>

#define N_NODES 100000
#define N_EDGES 1600000
#define HDIM 64
#define SCAN_T 1024
#define SCAN_CHUNK 98    // ceil(100000/1024)
#define NPB 128          // nodes per block
#define LBLOCKS 782      // ceil(100000/128)

// order-preserving float<->uint map: min-uint == min-float (non-NaN)
__device__ __forceinline__ unsigned encMin(float f) {
  unsigned u = __float_as_uint(f);
  return (u & 0x80000000u) ? ~u : (u | 0x80000000u);
}
__device__ __forceinline__ float decMin(unsigned u) {
  unsigned b = (u & 0x80000000u) ? (u & 0x7FFFFFFFu) : ~u;
  return __uint_as_float(b);
}

// ---------------- CSR build ----------------

__global__ __launch_bounds__(256) void k_zero_int(int* __restrict__ p, int n) {
  int i = blockIdx.x * 256 + threadIdx.x;
  if (i < n) p[i] = 0;
}

__global__ __launch_bounds__(256) void k_deg_count(const int* __restrict__ ei,
                                                   int* __restrict__ deg) {
  int e = blockIdx.x * 256 + threadIdx.x;
  if (e < N_EDGES) atomicAdd(&deg[ei[N_EDGES + e]], 1);
}

// single-block exclusive scan of deg[N] -> row_ptr[N+1]
__global__ __launch_bounds__(SCAN_T) void k_rowptr(const int* __restrict__ deg,
                                                   int* __restrict__ row_ptr) {
  __shared__ int sums[SCAN_T];
  const int t = threadIdx.x;
  const int lo = t * SCAN_CHUNK;
  const int hi = min(lo + SCAN_CHUNK, N_NODES);
  int s = 0;
  for (int i = lo; i < hi; ++i) s += deg[i];
  sums[t] = s;
  __syncthreads();
  for (int off = 1; off < SCAN_T; off <<= 1) {
    int v = (t >= off) ? sums[t - off] : 0;
    __syncthreads();
    sums[t] += v;
    __syncthreads();
  }
  int run = (t == 0) ? 0 : sums[t - 1];
  for (int i = lo; i < hi; ++i) { row_ptr[i] = run; run += deg[i]; }
  if (t == SCAN_T - 1) row_ptr[N_NODES] = run;
}

__global__ __launch_bounds__(256) void k_scatter(
    const int* __restrict__ ei, const float* __restrict__ eattr,
    const int* __restrict__ row_ptr, int* __restrict__ cursor,
    int* __restrict__ s_src, float* __restrict__ s_ea, int* __restrict__ s_dl) {
  int e = blockIdx.x * 256 + threadIdx.x;
  if (e >= N_EDGES) return;
  int d = ei[N_EDGES + e];
  int pos = row_ptr[d] + atomicAdd(&cursor[d], 1);
  s_src[pos] = ei[e];
  s_ea[pos] = eattr[e];
  s_dl[pos] = d & (NPB - 1);   // node-local index within its 128-node block
}

// ---------------- embed ----------------

// h = x*emb_w + emb_b (NF==1), then z = h @ W1a[0] + b1[0].
__global__ __launch_bounds__(256) void k_embed_z(
    const float* __restrict__ x, const float* __restrict__ emb_w,
    const float* __restrict__ emb_b,
    const float* __restrict__ w1, const float* __restrict__ b1,
    float* __restrict__ h, float* __restrict__ z) {
  __shared__ float hs[64][65];
  const int t = threadIdx.x;
  const int nl = t >> 2;
  const int l4 = t & 3;
  const int i = blockIdx.x * 64 + nl;
  const bool valid = (i < N_NODES);
  const int jbase = l4 * 16;
  const float xv = valid ? x[i] : 0.0f;

  float hv[16];
  #pragma unroll
  for (int jj = 0; jj < 16; ++jj) {
    int j = jbase + jj;
    hv[jj] = fmaf(xv, emb_w[j], emb_b[j]);
    hs[nl][j] = hv[jj];
  }
  if (valid) {
    #pragma unroll
    for (int q = 0; q < 4; ++q)
      reinterpret_cast<float4*>(h + (size_t)i * HDIM)[l4 * 4 + q] =
          make_float4(hv[4*q], hv[4*q+1], hv[4*q+2], hv[4*q+3]);
  }
  __syncthreads();

  float acc[16];
  #pragma unroll
  for (int jj = 0; jj < 16; ++jj) acc[jj] = b1[jbase + jj];
  #pragma unroll 8
  for (int k = 0; k < 64; ++k) {
    float hk = hs[nl][k];
    const float* wr = w1 + k * 64 + jbase;
    #pragma unroll
    for (int jj = 0; jj < 16; ++jj) acc[jj] = fmaf(hk, wr[jj], acc[jj]);
  }
  if (valid) {
    #pragma unroll
    for (int q = 0; q < 4; ++q)
      reinterpret_cast<float4*>(z + (size_t)i * HDIM)[l4 * 4 + q] =
          make_float4(acc[4*q], acc[4*q+1], acc[4*q+2], acc[4*q+3]);
  }
}

// ---------------- fused layer kernel ----------------
// Block = 256 threads (4 waves), 128 nodes, all their CSR edges (contiguous).
// AGGR: each wave takes a contiguous 1/4 of the block's edge range. Per
// 8-edge batch: 8 lanes cooperatively gather+relu one z-row (coalesced),
// stage to LDS; then GEMM with lane=column, W2 column in 64 VGPRs, hid via
// LDS same-address broadcast. Running min per column, flushed to LDS
// atomicMin (uint-encoded) on dst change. UPDATE: 2 threads/node × 32 cols,
// weights via wave-uniform s_load, h1/hn exchanged through the acc buffer.
template <int LAST>
__global__ __launch_bounds__(256) void k_layer(
    const int* __restrict__ row_ptr,
    const int* __restrict__ s_src, const float* __restrict__ s_ea,
    const int* __restrict__ s_dl,
    const float* __restrict__ z_in,
    const float* __restrict__ w1b, const float* __restrict__ w2,
    const float* __restrict__ b2,
    const float* __restrict__ u1w, const float* __restrict__ u1b,
    const float* __restrict__ u2w, const float* __restrict__ u2b,
    const float* __restrict__ w1next, const float* __restrict__ b1next,
    const float* __restrict__ fcw, const float* __restrict__ fcb,
    float* __restrict__ h, float* __restrict__ z_out, float* __restrict__ out) {
  __shared__ float hid_s[4][8][68];        // [wave][edge-in-batch][64+pad]
  __shared__ unsigned acc_u[NPB][65];      // min-accumulator / exchange buffer
  __shared__ float ps[NPB][2];
  float* acc_f = (float*)acc_u;            // same memory, float view

  const int t = threadIdx.x;
  const int lane = t & 63;
  const int w = __builtin_amdgcn_readfirstlane(t >> 6);
  const int nbase = blockIdx.x * NPB;

  // init accumulator to encoded "empty" (decodes to NaN -> 0)
  for (int i = t; i < NPB * 65; i += 256) ((unsigned*)acc_u)[i] = 0xFFFFFFFFu;
  __syncthreads();

  // ================= aggregation =================
  {
    const int eb0 = row_ptr[nbase];
    const int eb1 = row_ptr[min(nbase + NPB, N_NODES)];
    const int n = eb1 - eb0;
    const int we0 = eb0 + (n * w) / 4;
    const int we1 = eb0 + (n * (w + 1)) / 4;

    const int eL = lane >> 3;   // which edge of the batch (0..7)
    const int q  = lane & 7;    // which 16B quad-pair of the row (0..7)
    const float4 w1bA = ((const float4*)w1b)[q];
    const float4 w1bB = ((const float4*)w1b)[8 + q];
    const float b2c = b2[lane];
    float w2c[64];
    #pragma unroll
    for (int k = 0; k < 64; ++k) w2c[k] = w2[k * 64 + lane];   // coalesced

    float run = INFINITY;
    int cur = -1;

    float4 ra, rb; float eaR = 0.0f;
    ra = make_float4(0.f,0.f,0.f,0.f); rb = ra;
    if (we0 + eL < we1) {
      const int src = s_src[we0 + eL];
      const float4* zr = (const float4*)(z_in + (size_t)src * HDIM);
      ra = zr[q]; rb = zr[8 + q];
      eaR = s_ea[we0 + eL];
    }

    for (int b = we0; b < we1; b += 8) {
      // prefetch next batch into registers
      float4 na = make_float4(0.f,0.f,0.f,0.f), nb = na; float ean = 0.0f;
      if (b + 8 + eL < we1) {
        const int srcn = s_src[b + 8 + eL];
        const float4* zrn = (const float4*)(z_in + (size_t)srcn * HDIM);
        na = zrn[q]; nb = zrn[8 + q];
        ean = s_ea[b + 8 + eL];
      }
      // stage current batch: hid = relu(z + ea*w1b), 8 lanes per row
      if (b + eL < we1) {
        float4 h0, h1;
        h0.x = fmaxf(fmaf(eaR, w1bA.x, ra.x), 0.f);
        h0.y = fmaxf(fmaf(eaR, w1bA.y, ra.y), 0.f);
        h0.z = fmaxf(fmaf(eaR, w1bA.z, ra.z), 0.f);
        h0.w = fmaxf(fmaf(eaR, w1bA.w, ra.w), 0.f);
        h1.x = fmaxf(fmaf(eaR, w1bB.x, rb.x), 0.f);
        h1.y = fmaxf(fmaf(eaR, w1bB.y, rb.y), 0.f);
        h1.z = fmaxf(fmaf(eaR, w1bB.z, rb.z), 0.f);
        h1.w = fmaxf(fmaf(eaR, w1bB.w, rb.w), 0.f);
        *(float4*)&hid_s[w][eL][q * 4] = h0;
        *(float4*)&hid_s[w][eL][32 + q * 4] = h1;
      }
      // GEMM + min-merge for this batch (lane = output column)
      #pragma unroll
      for (int e2 = 0; e2 < 8; ++e2) {
        if (b + e2 >= we1) break;
        float m0 = b2c, m1 = 0.f, m2 = 0.f, m3 = 0.f;
        #pragma unroll
        for (int k4 = 0; k4 < 16; ++k4) {
          float4 hq = *(const float4*)&hid_s[w][e2][k4 * 4];  // broadcast
          m0 = fmaf(hq.x, w2c[4*k4+0], m0);
          m1 = fmaf(hq.y, w2c[4*k4+1], m1);
          m2 = fmaf(hq.z, w2c[4*k4+2], m2);
          m3 = fmaf(hq.w, w2c[4*k4+3], m3);
        }
        float m = (m0 + m1) + (m2 + m3);
        const int dl = s_dl[b + e2];   // wave-uniform
        if (dl != cur) {
          if (cur >= 0) atomicMin(&acc_u[cur][lane], encMin(run));
          cur = dl; run = INFINITY;
        }
        run = fminf(run, m);
      }
      ra = na; rb = nb; eaR = ean;
    }
    if (cur >= 0) atomicMin(&acc_u[cur][lane], encMin(run));
  }
  __syncthreads();

  // ================= update =================
  const int half = w & 1;
  const int pr = w >> 1;
  const int jb = half * 32;
  const int nl = pr * 64 + lane;             // 0..127
  const int node = nbase + nl;
  const bool valid = (node < N_NODES);
  const size_t off = (size_t)(valid ? node : 0) * HDIM;

  // decode own 32 cols in place (NaN from empty segments -> 0)
  #pragma unroll
  for (int j = 0; j < 32; ++j) {
    float f = decMin(acc_u[nl][jb + j]);
    if (!isfinite(f)) f = 0.f;
    acc_f[nl * 65 + jb + j] = f;
  }
  __syncthreads();

  // ---- phase 1: acc32 = (u @ U1 + b1)[jb..jb+32), u = [h(global), aggr(LDS)] ----
  float acc[32];
  #pragma unroll
  for (int j = 0; j < 32; ++j) acc[j] = u1b[jb + j];
  {
    const float4* hr = reinterpret_cast<const float4*>(h + off);
    for (int k4 = 0; k4 < 16; ++k4) {
      float4 uv = hr[k4];
      const float* w0 = u1w + (4*k4+0) * 64 + jb;
      const float* w1 = u1w + (4*k4+1) * 64 + jb;
      const float* w2r = u1w + (4*k4+2) * 64 + jb;
      const float* w3 = u1w + (4*k4+3) * 64 + jb;
      #pragma unroll
      for (int j = 0; j < 32; ++j) acc[j] = fmaf(uv.x, w0[j], acc[j]);
      #pragma unroll
      for (int j = 0; j < 32; ++j) acc[j] = fmaf(uv.y, w1[j], acc[j]);
      #pragma unroll
      for (int j = 0; j < 32; ++j) acc[j] = fmaf(uv.z, w2r[j], acc[j]);
      #pragma unroll
      for (int j = 0; j < 32; ++j) acc[j] = fmaf(uv.w, w3[j], acc[j]);
    }
    #pragma unroll 4
    for (int k = 0; k < 64; ++k) {
      float uk = acc_f[nl * 65 + k];
      const float* wr = u1w + (64 + k) * 64 + jb;
      #pragma unroll
      for (int j = 0; j < 32; ++j) acc[j] = fmaf(uk, wr[j], acc[j]);
    }
  }
  __syncthreads();   // all phase-1 LDS reads done before overwrite
  #pragma unroll
  for (int j = 0; j < 32; ++j) acc_f[nl * 65 + jb + j] = fmaxf(acc[j], 0.f);
  __syncthreads();

  // ---- phase 2: hn = (relu(h1) @ U2 + b2)[jb..jb+32) ----
  float hn[32];
  #pragma unroll
  for (int j = 0; j < 32; ++j) hn[j] = u2b[jb + j];
  #pragma unroll 4
  for (int k = 0; k < 64; ++k) {
    float hk = acc_f[nl * 65 + k];
    const float* wr = u2w + k * 64 + jb;
    #pragma unroll
    for (int j = 0; j < 32; ++j) hn[j] = fmaf(hk, wr[j], hn[j]);
  }
  if (valid) {
    #pragma unroll
    for (int v = 0; v < 8; ++v)
      reinterpret_cast<float4*>(h + off)[half * 8 + v] =
          make_float4(hn[4*v], hn[4*v+1], hn[4*v+2], hn[4*v+3]);
  }

  if (LAST) {
    float s = 0.0f;
    #pragma unroll
    for (int j = 0; j < 32; ++j) s = fmaf(hn[j], fcw[jb + j], s);
    ps[nl][half] = s;
    __syncthreads();
    if (half == 0 && valid) out[node] = ps[nl][0] + ps[nl][1] + fcb[0];
  } else {
    __syncthreads();   // all phase-2 LDS reads done
    #pragma unroll
    for (int j = 0; j < 32; ++j) acc_f[nl * 65 + jb + j] = hn[j];
    __syncthreads();
    // ---- phase 3: z_next = h_new @ W1a_next + b1_next ----
    float zz[32];
    #pragma unroll
    for (int j = 0; j < 32; ++j) zz[j] = b1next[jb + j];
    #pragma unroll 4
    for (int k = 0; k < 64; ++k) {
      float hk = acc_f[nl * 65 + k];
      const float* wr = w1next + k * 64 + jb;
      #pragma unroll
      for (int j = 0; j < 32; ++j) zz[j] = fmaf(hk, wr[j], zz[j]);
    }
    if (valid) {
      #pragma unroll
      for (int v = 0; v < 8; ++v)
        reinterpret_cast<float4*>(z_out + off)[half * 8 + v] =
            make_float4(zz[4*v], zz[4*v+1], zz[4*v+2], zz[4*v+3]);
    }
  }
}

extern "C" void kernel_launch(void* const* d_in, const int* in_sizes, int n_in,
                              void* d_out, int out_size, void* d_ws, size_t ws_size,
                              hipStream_t stream) {
  const float* x      = (const float*)d_in[0];
  const int*   ei     = (const int*)d_in[1];
  const float* eattr  = (const float*)d_in[2];
  const float* emb_w  = (const float*)d_in[3];
  const float* emb_b  = (const float*)d_in[4];
  const float* msg_w1 = (const float*)d_in[5];
  const float* msg_b1 = (const float*)d_in[6];
  const float* msg_w2 = (const float*)d_in[7];
  const float* msg_b2 = (const float*)d_in[8];
  const float* upd_w1 = (const float*)d_in[9];
  const float* upd_b1 = (const float*)d_in[10];
  const float* upd_w2 = (const float*)d_in[11];
  const float* upd_b2 = (const float*)d_in[12];
  const float* fc_w   = (const float*)d_in[13];
  const float* fc_b   = (const float*)d_in[14];
  float* out = (float*)d_out;

  // workspace layout
  float* h     = (float*)d_ws;                          // N*64
  float* zA    = h + (size_t)N_NODES * HDIM;            // N*64
  float* zB    = zA + (size_t)N_NODES * HDIM;           // N*64
  float* s_ea  = zB + (size_t)N_NODES * HDIM;           // E
  int*   s_src = (int*)(s_ea + N_EDGES);                // E
  int*   s_dl  = s_src + N_EDGES;                       // E
  int*   row_ptr = s_dl + N_EDGES;                      // N+1
  int*   deg   = row_ptr + (N_NODES + 1);               // N
  int*   cursor= deg + N_NODES;                         // N (contiguous w/ deg)

  const int nodeBlocks64 = (N_NODES + 63) / 64;
  const int edgeBlocks = (N_EDGES + 255) / 256;

  // ---- CSR build (per launch; ws re-poisoned every call) ----
  k_zero_int<<<(2 * N_NODES + 255) / 256, 256, 0, stream>>>(deg, 2 * N_NODES);
  k_deg_count<<<edgeBlocks, 256, 0, stream>>>(ei, deg);
  k_rowptr<<<1, SCAN_T, 0, stream>>>(deg, row_ptr);
  k_scatter<<<edgeBlocks, 256, 0, stream>>>(ei, eattr, row_ptr, cursor,
                                            s_src, s_ea, s_dl);

  // ---- embed + fused layers ----
  k_embed_z<<<nodeBlocks64, 256, 0, stream>>>(x, emb_w, emb_b, msg_w1, msg_b1, h, zA);

  float* zin = zA;
  float* zout = zB;
  for (int l = 0; l < 5; ++l) {
    const float* w1b = msg_w1 + l * 65 * 64 + 64 * 64;  // row 64: edge_attr coeffs
    const float* w2  = msg_w2 + l * 64 * 64;
    const float* b2  = msg_b2 + l * 64;
    const float* u1w = upd_w1 + l * 128 * 64;
    const float* u1b = upd_b1 + l * 64;
    const float* u2w = upd_w2 + l * 64 * 64;
    const float* u2b = upd_b2 + l * 64;
    if (l < 4) {
      k_layer<0><<<LBLOCKS, 256, 0, stream>>>(
          row_ptr, s_src, s_ea, s_dl, zin,
          w1b, w2, b2, u1w, u1b, u2w, u2b,
          msg_w1 + (l + 1) * 65 * 64, msg_b1 + (l + 1) * 64,
          nullptr, nullptr,
          h, zout, nullptr);
      float* tmp = zin; zin = zout; zout = tmp;
    } else {
      k_layer<1><<<LBLOCKS, 256, 0, stream>>>(
          row_ptr, s_src, s_ea, s_dl, zin,
          w1b, w2, b2, u1w, u1b, u2w, u2b,
          nullptr, nullptr,
          fc_w, fc_b,
          h, nullptr, out);
    }
  }
}

// Round 7
// 2218.963 us; speedup vs baseline: 2.1317x; 1.1538x over previous
//
#include <hip/hip_runtime.h>
#include <math.h>

#define N_NODES 100000
#define N_EDGES 1600000
#define HDIM 64
#define SCAN_T 1024
#define SCAN_CHUNK 98    // ceil(100000/1024)
#define NPB 64           // nodes per block
#define LBLOCKS 1563     // ceil(100000/64)
#define BSTRIDE 66       // LDS row stride (floats): 8B-aligned rows, 2-way banks

// order-preserving float<->uint map: min-uint == min-float (non-NaN)
__device__ __forceinline__ unsigned encMin(float f) {
  unsigned u = __float_as_uint(f);
  return (u & 0x80000000u) ? ~u : (u | 0x80000000u);
}
__device__ __forceinline__ float decMin(unsigned u) {
  unsigned b = (u & 0x80000000u) ? (u & 0x7FFFFFFFu) : ~u;
  return __uint_as_float(b);
}

// ---------------- CSR build ----------------

__global__ __launch_bounds__(256) void k_zero_int(int* __restrict__ p, int n) {
  int i = blockIdx.x * 256 + threadIdx.x;
  if (i < n) p[i] = 0;
}

__global__ __launch_bounds__(256) void k_deg_count(const int* __restrict__ ei,
                                                   int* __restrict__ deg) {
  int e = blockIdx.x * 256 + threadIdx.x;
  if (e < N_EDGES) atomicAdd(&deg[ei[N_EDGES + e]], 1);
}

// single-block exclusive scan of deg[N] -> row_ptr[N+1]
__global__ __launch_bounds__(SCAN_T) void k_rowptr(const int* __restrict__ deg,
                                                   int* __restrict__ row_ptr) {
  __shared__ int sums[SCAN_T];
  const int t = threadIdx.x;
  const int lo = t * SCAN_CHUNK;
  const int hi = min(lo + SCAN_CHUNK, N_NODES);
  int s = 0;
  for (int i = lo; i < hi; ++i) s += deg[i];
  sums[t] = s;
  __syncthreads();
  for (int off = 1; off < SCAN_T; off <<= 1) {
    int v = (t >= off) ? sums[t - off] : 0;
    __syncthreads();
    sums[t] += v;
    __syncthreads();
  }
  int run = (t == 0) ? 0 : sums[t - 1];
  for (int i = lo; i < hi; ++i) { row_ptr[i] = run; run += deg[i]; }
  if (t == SCAN_T - 1) row_ptr[N_NODES] = run;
}

__global__ __launch_bounds__(256) void k_scatter(
    const int* __restrict__ ei, const float* __restrict__ eattr,
    const int* __restrict__ row_ptr, int* __restrict__ cursor,
    int* __restrict__ s_src, float* __restrict__ s_ea, int* __restrict__ s_dl) {
  int e = blockIdx.x * 256 + threadIdx.x;
  if (e >= N_EDGES) return;
  int d = ei[N_EDGES + e];
  int pos = row_ptr[d] + atomicAdd(&cursor[d], 1);
  s_src[pos] = ei[e];
  s_ea[pos] = eattr[e];
  s_dl[pos] = d & (NPB - 1);   // node-local index within its 64-node block
}

// ---------------- embed ----------------

// h = x*emb_w + emb_b (NF==1), then z = h @ W1a[0] + b1[0].
__global__ __launch_bounds__(256) void k_embed_z(
    const float* __restrict__ x, const float* __restrict__ emb_w,
    const float* __restrict__ emb_b,
    const float* __restrict__ w1, const float* __restrict__ b1,
    float* __restrict__ h, float* __restrict__ z) {
  __shared__ float hs[64][65];
  const int t = threadIdx.x;
  const int nl = t >> 2;
  const int l4 = t & 3;
  const int i = blockIdx.x * 64 + nl;
  const bool valid = (i < N_NODES);
  const int jbase = l4 * 16;
  const float xv = valid ? x[i] : 0.0f;

  float hv[16];
  #pragma unroll
  for (int jj = 0; jj < 16; ++jj) {
    int j = jbase + jj;
    hv[jj] = fmaf(xv, emb_w[j], emb_b[j]);
    hs[nl][j] = hv[jj];
  }
  if (valid) {
    #pragma unroll
    for (int q = 0; q < 4; ++q)
      reinterpret_cast<float4*>(h + (size_t)i * HDIM)[l4 * 4 + q] =
          make_float4(hv[4*q], hv[4*q+1], hv[4*q+2], hv[4*q+3]);
  }
  __syncthreads();

  float acc[16];
  #pragma unroll
  for (int jj = 0; jj < 16; ++jj) acc[jj] = b1[jbase + jj];
  #pragma unroll 8
  for (int k = 0; k < 64; ++k) {
    float hk = hs[nl][k];
    const float* wr = w1 + k * 64 + jbase;
    #pragma unroll
    for (int jj = 0; jj < 16; ++jj) acc[jj] = fmaf(hk, wr[jj], acc[jj]);
  }
  if (valid) {
    #pragma unroll
    for (int q = 0; q < 4; ++q)
      reinterpret_cast<float4*>(z + (size_t)i * HDIM)[l4 * 4 + q] =
          make_float4(acc[4*q], acc[4*q+1], acc[4*q+2], acc[4*q+3]);
  }
}

// ---------------- fused layer kernel ----------------
// 256 threads = 4 waves = 2 wave-pairs; 64 nodes/block; the block's CSR edge
// range is split in half between the pairs. Per 64-edge batch:
//  stage: coalesced gather of z rows (8 lanes/row, 128B segments), relu+ea,
//         write rows to LDS (b64, stride 66 -> aligned, 2-way banks).
//  GEMM:  lane = edge. hid from own LDS row (b64); W2/b2 wave-uniform ->
//         SGPR operands (zero LDS, zero L1); wave wi computes 32 cols.
//  merge: m transposed through LDS; lane = col, dst index wave-uniform scalar;
//         runs flushed to block accumulator via LDS atomicMin (encoded).
// UPDATE: 4 threads/node x 16 cols, weights via s_load, exchange in acc buf.
template <int LAST>
__global__ __launch_bounds__(256) void k_layer(
    const int* __restrict__ row_ptr,
    const int* __restrict__ s_src, const float* __restrict__ s_ea,
    const int* __restrict__ s_dl,
    const float* __restrict__ z_in,
    const float* __restrict__ w1b, const float* __restrict__ w2,
    const float* __restrict__ b2,
    const float* __restrict__ u1w, const float* __restrict__ u1b,
    const float* __restrict__ u2w, const float* __restrict__ u2b,
    const float* __restrict__ w1next, const float* __restrict__ b1next,
    const float* __restrict__ fcw, const float* __restrict__ fcb,
    float* __restrict__ h, float* __restrict__ z_out, float* __restrict__ out) {
  __shared__ float buf[2][64][BSTRIDE];    // per-pair edge-row buffer
  __shared__ unsigned acc_u[NPB][65];      // block min-accumulator / exchange
  __shared__ float ps[NPB][4];
  float* acc_f = (float*)acc_u;

  const int t = threadIdx.x;
  const int lane = t & 63;
  const int w = __builtin_amdgcn_readfirstlane(t >> 6);
  const int pair = w >> 1;                 // 0,1
  const int wi = w & 1;                    // wave within pair
  const int nbase = blockIdx.x * NPB;

  // init accumulator to encoded "empty" (decodes to NaN -> 0)
  for (int i = t; i < NPB * 65; i += 256) ((unsigned*)acc_u)[i] = 0xFFFFFFFFu;

  const int eb0 = row_ptr[nbase];
  const int eb1 = row_ptr[min(nbase + NPB, N_NODES)];
  const int n = eb1 - eb0;
  const int emid = eb0 + (n >> 1);
  const int p0 = pair ? emid : eb0;
  const int p1 = pair ? eb1 : emid;
  const int nbat = ((n - (n >> 1)) + 63) >> 6;   // max(n0,n1)=n-n/2

  const int rq = lane >> 3;                // row-in-group 0..7
  const int q  = lane & 7;                 // quad 0..7
  const float4 w1bA = ((const float4*)w1b)[q];
  const float4 w1bB = ((const float4*)w1b)[q + 8];
  const int jb = wi * 32;

  __syncthreads();

  for (int bi = 0; bi < nbat; ++bi) {
    const int base = p0 + (bi << 6);
    const int cnt  = min(64, p1 - base);   // may be <= 0

    // ---- stage rows [wi*32, wi*32+32) of this batch ----
    if (cnt > 0) {
      #pragma unroll
      for (int i = 0; i < 4; ++i) {
        const int row = wi * 32 + i * 8 + rq;
        const int ed = base + row;
        const bool v = (row < cnt);
        const int src = v ? s_src[ed] : 0;
        const float ea = v ? s_ea[ed] : 0.0f;
        const float4* zr = (const float4*)(z_in + (size_t)src * HDIM);
        float4 a = zr[q];
        float4 b = zr[q + 8];
        float2 h0, h1, h2, h3;
        h0.x = fmaxf(fmaf(ea, w1bA.x, a.x), 0.f);
        h0.y = fmaxf(fmaf(ea, w1bA.y, a.y), 0.f);
        h1.x = fmaxf(fmaf(ea, w1bA.z, a.z), 0.f);
        h1.y = fmaxf(fmaf(ea, w1bA.w, a.w), 0.f);
        h2.x = fmaxf(fmaf(ea, w1bB.x, b.x), 0.f);
        h2.y = fmaxf(fmaf(ea, w1bB.y, b.y), 0.f);
        h3.x = fmaxf(fmaf(ea, w1bB.z, b.z), 0.f);
        h3.y = fmaxf(fmaf(ea, w1bB.w, b.w), 0.f);
        float* bp = &buf[pair][row][0];
        *(float2*)&bp[q * 4]          = h0;
        *(float2*)&bp[q * 4 + 2]      = h1;
        *(float2*)&bp[32 + q * 4]     = h2;
        *(float2*)&bp[32 + q * 4 + 2] = h3;
      }
    }
    __syncthreads();

    // ---- GEMM: lane = edge, cols [jb, jb+32); W2 via SGPR ----
    float m[32];
    if (cnt > 0) {
      #pragma unroll
      for (int c = 0; c < 32; ++c) m[c] = b2[jb + c];
      const float* bp = &buf[pair][lane][0];
      #pragma unroll 4
      for (int k2 = 0; k2 < 32; ++k2) {
        float2 hq = *(const float2*)&bp[k2 * 2];
        const float* wr0 = w2 + (2 * k2 + 0) * 64 + jb;   // wave-uniform
        const float* wr1 = w2 + (2 * k2 + 1) * 64 + jb;
        #pragma unroll
        for (int c = 0; c < 32; ++c) m[c] = fmaf(hq.x, wr0[c], m[c]);
        #pragma unroll
        for (int c = 0; c < 32; ++c) m[c] = fmaf(hq.y, wr1[c], m[c]);
      }
    }
    __syncthreads();   // all GEMM reads of buf done

    // ---- write m back (transpose via LDS) ----
    if (cnt > 0) {
      float* bp = &buf[pair][lane][jb];
      #pragma unroll
      for (int c2 = 0; c2 < 16; ++c2)
        *(float2*)&bp[c2 * 2] = make_float2(m[2*c2], m[2*c2+1]);
    }
    __syncthreads();

    // ---- merge: lane = col; wave wi scans edges [wi*32, min(wi*32+32,cnt)) ----
    if (cnt > 0) {
      const int e0 = wi * 32;
      const int e1 = min(wi * 32 + 32, cnt);
      float run = INFINITY;
      int cur = -1;
      for (int e = e0; e < e1; ++e) {
        const int dl = s_dl[base + e];     // wave-uniform (s_load)
        if (dl != cur) {
          if (cur >= 0) atomicMin(&acc_u[cur][lane], encMin(run));
          cur = dl; run = INFINITY;
        }
        run = fminf(run, buf[pair][e][lane]);
      }
      if (cur >= 0) atomicMin(&acc_u[cur][lane], encMin(run));
    }
    __syncthreads();
  }

  // ================= update: 4 threads/node, 16 cols =================
  const int jq = w * 16;                   // wave-uniform col base
  const int node = nbase + lane;
  const bool valid = (node < N_NODES);
  const size_t off = (size_t)(valid ? node : 0) * HDIM;

  // decode own 16 cols in place (NaN from empty segments -> 0)
  #pragma unroll
  for (int j = 0; j < 16; ++j) {
    float f = decMin(acc_u[lane][jq + j]);
    if (!isfinite(f)) f = 0.f;
    acc_f[lane * 65 + jq + j] = f;
  }
  __syncthreads();

  // ---- phase 1: acc16 = (u @ U1 + b1)[jq..), u = [h(global), aggr(LDS)] ----
  float acc[16];
  #pragma unroll
  for (int j = 0; j < 16; ++j) acc[j] = u1b[jq + j];
  {
    const float4* hr = reinterpret_cast<const float4*>(h + off);
    for (int k4 = 0; k4 < 16; ++k4) {
      float4 uv = hr[k4];
      const float* w0 = u1w + (4*k4+0) * 64 + jq;
      const float* w1 = u1w + (4*k4+1) * 64 + jq;
      const float* w2r = u1w + (4*k4+2) * 64 + jq;
      const float* w3 = u1w + (4*k4+3) * 64 + jq;
      #pragma unroll
      for (int j = 0; j < 16; ++j) acc[j] = fmaf(uv.x, w0[j], acc[j]);
      #pragma unroll
      for (int j = 0; j < 16; ++j) acc[j] = fmaf(uv.y, w1[j], acc[j]);
      #pragma unroll
      for (int j = 0; j < 16; ++j) acc[j] = fmaf(uv.z, w2r[j], acc[j]);
      #pragma unroll
      for (int j = 0; j < 16; ++j) acc[j] = fmaf(uv.w, w3[j], acc[j]);
    }
    #pragma unroll 4
    for (int k = 0; k < 64; ++k) {
      float uk = acc_f[lane * 65 + k];
      const float* wr = u1w + (64 + k) * 64 + jq;
      #pragma unroll
      for (int j = 0; j < 16; ++j) acc[j] = fmaf(uk, wr[j], acc[j]);
    }
  }
  __syncthreads();   // phase-1 LDS reads done before overwrite
  #pragma unroll
  for (int j = 0; j < 16; ++j) acc_f[lane * 65 + jq + j] = fmaxf(acc[j], 0.f);
  __syncthreads();

  // ---- phase 2: hn = (relu(h1) @ U2 + b2)[jq..) ----
  float hn[16];
  #pragma unroll
  for (int j = 0; j < 16; ++j) hn[j] = u2b[jq + j];
  #pragma unroll 4
  for (int k = 0; k < 64; ++k) {
    float hk = acc_f[lane * 65 + k];
    const float* wr = u2w + k * 64 + jq;
    #pragma unroll
    for (int j = 0; j < 16; ++j) hn[j] = fmaf(hk, wr[j], hn[j]);
  }
  if (valid) {
    #pragma unroll
    for (int v4 = 0; v4 < 4; ++v4)
      reinterpret_cast<float4*>(h + off)[w * 4 + v4] =
          make_float4(hn[4*v4], hn[4*v4+1], hn[4*v4+2], hn[4*v4+3]);
  }

  if (LAST) {
    float s = 0.0f;
    #pragma unroll
    for (int j = 0; j < 16; ++j) s = fmaf(hn[j], fcw[jq + j], s);
    ps[lane][w] = s;
    __syncthreads();
    if (w == 0 && valid)
      out[node] = ps[lane][0] + ps[lane][1] + ps[lane][2] + ps[lane][3] + fcb[0];
  } else {
    __syncthreads();   // phase-2 LDS reads done
    #pragma unroll
    for (int j = 0; j < 16; ++j) acc_f[lane * 65 + jq + j] = hn[j];
    __syncthreads();
    // ---- phase 3: z_next = h_new @ W1a_next + b1_next ----
    float zz[16];
    #pragma unroll
    for (int j = 0; j < 16; ++j) zz[j] = b1next[jq + j];
    #pragma unroll 4
    for (int k = 0; k < 64; ++k) {
      float hk = acc_f[lane * 65 + k];
      const float* wr = w1next + k * 64 + jq;
      #pragma unroll
      for (int j = 0; j < 16; ++j) zz[j] = fmaf(hk, wr[j], zz[j]);
    }
    if (valid) {
      #pragma unroll
      for (int v4 = 0; v4 < 4; ++v4)
        reinterpret_cast<float4*>(z_out + off)[w * 4 + v4] =
            make_float4(zz[4*v4], zz[4*v4+1], zz[4*v4+2], zz[4*v4+3]);
    }
  }
}

extern "C" void kernel_launch(void* const* d_in, const int* in_sizes, int n_in,
                              void* d_out, int out_size, void* d_ws, size_t ws_size,
                              hipStream_t stream) {
  const float* x      = (const float*)d_in[0];
  const int*   ei     = (const int*)d_in[1];
  const float* eattr  = (const float*)d_in[2];
  const float* emb_w  = (const float*)d_in[3];
  const float* emb_b  = (const float*)d_in[4];
  const float* msg_w1 = (const float*)d_in[5];
  const float* msg_b1 = (const float*)d_in[6];
  const float* msg_w2 = (const float*)d_in[7];
  const float* msg_b2 = (const float*)d_in[8];
  const float* upd_w1 = (const float*)d_in[9];
  const float* upd_b1 = (const float*)d_in[10];
  const float* upd_w2 = (const float*)d_in[11];
  const float* upd_b2 = (const float*)d_in[12];
  const float* fc_w   = (const float*)d_in[13];
  const float* fc_b   = (const float*)d_in[14];
  float* out = (float*)d_out;

  // workspace layout
  float* h     = (float*)d_ws;                          // N*64
  float* zA    = h + (size_t)N_NODES * HDIM;            // N*64
  float* zB    = zA + (size_t)N_NODES * HDIM;           // N*64
  float* s_ea  = zB + (size_t)N_NODES * HDIM;           // E
  int*   s_src = (int*)(s_ea + N_EDGES);                // E
  int*   s_dl  = s_src + N_EDGES;                       // E
  int*   row_ptr = s_dl + N_EDGES;                      // N+1
  int*   deg   = row_ptr + (N_NODES + 1);               // N
  int*   cursor= deg + N_NODES;                         // N (contiguous w/ deg)

  const int nodeBlocks64 = (N_NODES + 63) / 64;
  const int edgeBlocks = (N_EDGES + 255) / 256;

  // ---- CSR build (per launch; ws re-poisoned every call) ----
  k_zero_int<<<(2 * N_NODES + 255) / 256, 256, 0, stream>>>(deg, 2 * N_NODES);
  k_deg_count<<<edgeBlocks, 256, 0, stream>>>(ei, deg);
  k_rowptr<<<1, SCAN_T, 0, stream>>>(deg, row_ptr);
  k_scatter<<<edgeBlocks, 256, 0, stream>>>(ei, eattr, row_ptr, cursor,
                                            s_src, s_ea, s_dl);

  // ---- embed + fused layers ----
  k_embed_z<<<nodeBlocks64, 256, 0, stream>>>(x, emb_w, emb_b, msg_w1, msg_b1, h, zA);

  float* zin = zA;
  float* zout = zB;
  for (int l = 0; l < 5; ++l) {
    const float* w1b = msg_w1 + l * 65 * 64 + 64 * 64;  // row 64: edge_attr coeffs
    const float* w2  = msg_w2 + l * 64 * 64;
    const float* b2  = msg_b2 + l * 64;
    const float* u1w = upd_w1 + l * 128 * 64;
    const float* u1b = upd_b1 + l * 64;
    const float* u2w = upd_w2 + l * 64 * 64;
    const float* u2b = upd_b2 + l * 64;
    if (l < 4) {
      k_layer<0><<<LBLOCKS, 256, 0, stream>>>(
          row_ptr, s_src, s_ea, s_dl, zin,
          w1b, w2, b2, u1w, u1b, u2w, u2b,
          msg_w1 + (l + 1) * 65 * 64, msg_b1 + (l + 1) * 64,
          nullptr, nullptr,
          h, zout, nullptr);
      float* tmp = zin; zin = zout; zout = tmp;
    } else {
      k_layer<1><<<LBLOCKS, 256, 0, stream>>>(
          row_ptr, s_src, s_ea, s_dl, zin,
          w1b, w2, b2, u1w, u1b, u2w, u2b,
          nullptr, nullptr,
          fc_w, fc_b,
          h, nullptr, out);
    }
  }
}